// Round 6
// baseline (1535.420 us; speedup 1.0000x reference)
//
#include <hip/hip_runtime.h>

#define SS 1024
#define BB 2048
#define NT 256
#define GRID 512   // 4 waves/block, 1 batch/wave -> 2048 batches

typedef unsigned int u32;
typedef unsigned short u16;
typedef _Float16 half2v __attribute__((ext_vector_type(2)));
typedef __fp16 fp16x2 __attribute__((ext_vector_type(2)));

#define LDS_FENCE() asm volatile("s_waitcnt lgkmcnt(0)" ::: "memory")

// ---------- helpers ----------
__device__ __forceinline__ u16 f2bf(float f) {  // RNE fp32->bf16
  u32 u = __float_as_uint(f);
  return (u16)((u + 0x7fffu + ((u >> 16) & 1u)) >> 16);
}
template<bool BFM>
__device__ __forceinline__ float ldin(const void* p, int i) {
  if (BFM) { u16 v = ((const u16*)p)[i]; return __uint_as_float(((u32)v) << 16); }
  return ((const float*)p)[i];
}
__device__ __forceinline__ u32 packrtz(float lo, float hi) {
#if __has_builtin(__builtin_amdgcn_cvt_pkrtz)
  fp16x2 h = __builtin_amdgcn_cvt_pkrtz(lo, hi);
  return __builtin_bit_cast(u32, h);
#else
  _Float16 ha = (_Float16)lo, hb = (_Float16)hi;
  return (u32)__builtin_bit_cast(u16, ha) | ((u32)__builtin_bit_cast(u16, hb) << 16);
#endif
}
// load weight elems {i, i+1} (i even) -> packed f16x2 (bf16->f16 exact)
template<bool BFM>
__device__ __forceinline__ u32 ldpack(const void* p, int i) {
  if (BFM) {
    u32 pr = *(const u32*)((const u16*)p + i);
    return packrtz(__uint_as_float(pr << 16), __uint_as_float(pr & 0xffff0000u));
  }
  return packrtz(((const float*)p)[i], ((const float*)p)[i + 1]);
}
__device__ __forceinline__ float sigf(float x) {
  return __builtin_amdgcn_rcpf(1.0f + __expf(-x));
}
__device__ __forceinline__ float tanh_f(float x) {
  return 1.0f - 2.0f * __builtin_amdgcn_rcpf(__expf(2.0f * x) + 1.0f);
}
__device__ __forceinline__ float combine(const float acc[4], float& c) {
  float ig = sigf(acc[0]);
  float fg = sigf(acc[1]);
  float gg = tanh_f(acc[2]);
  float og = sigf(acc[3]);
  c = fg * c + ig * gg;
  return og * tanh_f(c);
}
// packed f16 dual-MAC into f32
__device__ __forceinline__ float dot2f(u32 w, u32 h, float acc) {
#if __has_builtin(__builtin_amdgcn_fdot2)
  return __builtin_amdgcn_fdot2(__builtin_bit_cast(half2v, w),
                                __builtin_bit_cast(half2v, h), acc, false);
#else
  half2v a = __builtin_bit_cast(half2v, w), b = __builtin_bit_cast(half2v, h);
  acc = fmaf((float)a.x, (float)b.x, acc);
  return fmaf((float)a.y, (float)b.y, acc);
#endif
}

template<bool BFM>
__device__ __forceinline__ void run(
    const void* xg,
    const void* Wih_f0, const void* Whh_f0, const void* b_f0,
    const void* Wih_f1, const void* Whh_f1, const void* b_f1,
    const void* Wih_b0, const void* Whh_b0, const void* b_b0,
    const void* Wih_b1, const void* Whh_b1, const void* b_b1,
    const void* Wlin, const void* blin, const int* futp, void* outp,
    _Float16 (*h0)[2][32], _Float16 (*h1)[32], int tid, int bid) {
  const int wv = tid >> 6, lane = tid & 63;
  const int j = lane & 31, dir = lane >> 5;   // dir 0: f0/f1 cells, dir 1: b0/b1 cells
  const int gb = bid * 4 + wv;                // 1 batch per wave

  const void* s0  = dir ? Whh_b0 : Whh_f0;
  const void* sA  = dir ? Wih_b1 : Wih_f1;
  const void* sB  = dir ? Whh_b1 : Whh_f1;
  const void* pb0 = dir ? b_b0 : b_f0;
  const void* pb1 = dir ? b_b1 : b_f1;
  const void* pwx = dir ? Wih_b0 : Wih_f0;

  // ---- per-lane weight residency: 192 dw packed f16x2 ----
  u32 w0[64];    // layer-0 rec: 4 gates x 16 dw (K=32)
  u32 w1[128];   // layer-1:     4 gates x (16 inp + 16 rec) dw (K=64)
#pragma unroll
  for (int g = 0; g < 4; ++g) {
    const int r = (g * 32 + j) * 32;
#pragma unroll
    for (int d = 0; d < 16; ++d) w0[g * 16 + d] = ldpack<BFM>(s0, r + 2 * d);
#pragma unroll
    for (int d = 0; d < 16; ++d) w1[g * 32 + d] = ldpack<BFM>(sA, r + 2 * d);
#pragma unroll
    for (int d = 0; d < 16; ++d) w1[g * 32 + 16 + d] = ldpack<BFM>(sB, r + 2 * d);
  }
  // layer-0 input weight + bias folded: (wx, b) . (x, 1) via one dot2
  u32 wb0[4];
  float b1v[4];
#pragma unroll
  for (int g = 0; g < 4; ++g) {
    wb0[g] = packrtz(ldin<BFM>(pwx, g * 32 + j), ldin<BFM>(pb0, g * 32 + j));
    b1v[g] = ldin<BFM>(pb1, g * 32 + j);
  }
  const float wl  = ldin<BFM>(Wlin, dir * 32 + j);
  const float blv = ldin<BFM>(blin, 0);
  const int fut = *futp;

  _Float16* const my0  = &h0[wv][dir][0];
  _Float16* const myh1 = &h1[wv][0];
  my0[j] = (_Float16)0.f;
  if (!dir) myh1[j] = (_Float16)0.f;
  LDS_FENCE();

  // fwd lanes compute step t=u; bwd lanes run one step skewed (t' = u-1).
  float c0 = 0.f, c1 = 0.f, h1prev = 0.f;
  float x_cur = ldin<BFM>(xg, (dir ? ((fut + 1) & (SS - 1)) : 0) * BB + gb);

  for (int u = 0; u <= SS; ++u) {
    int idxn = dir ? ((fut - u) & (SS - 1)) : ((u + 1 < SS) ? (u + 1) : (SS - 1));
    float x_n = ldin<BFM>(xg, idxn * BB + gb);

    // ---- layer 0 (fwd: f0@u ; bwd: b0@u-1) ----
    float acc[4];
    {
      const u32 xpk = packrtz(x_cur, 1.0f);
#pragma unroll
      for (int g = 0; g < 4; ++g) acc[g] = dot2f(wb0[g], xpk, 0.0f);
      const uint4* hp = (const uint4*)my0;
#pragma unroll
      for (int q = 0; q < 4; ++q) {
        uint4 hq = hp[q];
#pragma unroll
        for (int g = 0; g < 4; ++g) {
          acc[g] = dot2f(w0[g * 16 + 4 * q + 0], hq.x, acc[g]);
          acc[g] = dot2f(w0[g * 16 + 4 * q + 1], hq.y, acc[g]);
          acc[g] = dot2f(w0[g * 16 + 4 * q + 2], hq.z, acc[g]);
          acc[g] = dot2f(w0[g * 16 + 4 * q + 3], hq.w, acc[g]);
        }
      }
    }
    float hn0 = combine(acc, c0);
    if ((u == 0) && dir) { hn0 = 0.f; c0 = 0.f; }   // bwd u=0 computed t'=-1 garbage
    my0[j] = (_Float16)hn0;
    LDS_FENCE();

    // ---- layer 1 (fwd: f1@u rec=hf1(u-1) ; bwd: b1@u-1 rec=NEW hf1(u-1) per ref bug) ----
#pragma unroll
    for (int g = 0; g < 4; ++g) acc[g] = b1v[g];
    {
      const uint4* hp = (const uint4*)my0;            // inp: own new layer-0 h
#pragma unroll
      for (int q = 0; q < 4; ++q) {
        uint4 hq = hp[q];
#pragma unroll
        for (int g = 0; g < 4; ++g) {
          acc[g] = dot2f(w1[g * 32 + 4 * q + 0], hq.x, acc[g]);
          acc[g] = dot2f(w1[g * 32 + 4 * q + 1], hq.y, acc[g]);
          acc[g] = dot2f(w1[g * 32 + 4 * q + 2], hq.z, acc[g]);
          acc[g] = dot2f(w1[g * 32 + 4 * q + 3], hq.w, acc[g]);
        }
      }
      const uint4* hr = (const uint4*)myh1;           // rec: hf1 (pre-update)
#pragma unroll
      for (int q = 0; q < 4; ++q) {
        uint4 hq = hr[q];
#pragma unroll
        for (int g = 0; g < 4; ++g) {
          acc[g] = dot2f(w1[g * 32 + 16 + 4 * q + 0], hq.x, acc[g]);
          acc[g] = dot2f(w1[g * 32 + 16 + 4 * q + 1], hq.y, acc[g]);
          acc[g] = dot2f(w1[g * 32 + 16 + 4 * q + 2], hq.z, acc[g]);
          acc[g] = dot2f(w1[g * 32 + 16 + 4 * q + 3], hq.w, acc[g]);
        }
      }
    }
    float hn1 = combine(acc, c1);
    if ((u == 0) && dir) c1 = 0.f;

    // ---- output head for t'=u-1 ----
    float myh = dir ? hn1 : h1prev;
    float contrib = wl * myh;
#pragma unroll
    for (int m = 1; m <= 32; m <<= 1) contrib += __shfl_xor(contrib, m, 64);
    if (u > 0 && lane == 0) {
      float o = contrib + blv;
      size_t pos = (size_t)gb * SS + (size_t)(u - 1);
      if (BFM) ((u16*)outp)[pos] = f2bf(o);
      else     ((float*)outp)[pos] = o;
    }
    h1prev = hn1;

    if (u < SS && !dir) myh1[j] = (_Float16)hn1;  // publish hf1(u) for next iter's bwd
    LDS_FENCE();
    x_cur = x_n;
  }
}

// waves_per_eu pinned to (2,2): allocator must budget 256 VGPRs/wave instead of
// spilling 190 dw of weights to scratch to chase 4 waves/EU (R3/R5: 86 MB WRITE_SIZE).
__global__ __launch_bounds__(NT)
__attribute__((amdgpu_waves_per_eu(2, 2)))
void lstm_kernel(
    const void* __restrict__ xg,
    const void* Wih_f0, const void* Whh_f0, const void* b_f0,
    const void* Wih_f1, const void* Whh_f1, const void* b_f1,
    const void* Wih_b0, const void* Whh_b0, const void* b_b0,
    const void* Wih_b1, const void* Whh_b1, const void* b_b1,
    const void* Wlin, const void* blin, const int* __restrict__ futp,
    void* __restrict__ outp) {
  __shared__ __align__(16) _Float16 h0s[4][2][32];
  __shared__ __align__(16) _Float16 h1s[4][32];

  // dtype detection (uniform): bf16-pairs read as fp32 are implausible as N(0,1)
  bool bfm;
  {
    const float* xf = (const float*)xg;
    int bad = 0;
    for (int i = 0; i < 64; ++i) {
      float a = fabsf(xf[i]);
      bool ok = (a == 0.0f) || (a > 1e-8f && a < 1e4f);
      if (!ok) bad = 1;
    }
    bfm = (bad != 0);
  }

  if (bfm)
    run<true>(xg, Wih_f0, Whh_f0, b_f0, Wih_f1, Whh_f1, b_f1,
              Wih_b0, Whh_b0, b_b0, Wih_b1, Whh_b1, b_b1,
              Wlin, blin, futp, outp, h0s, h1s, threadIdx.x, blockIdx.x);
  else
    run<false>(xg, Wih_f0, Whh_f0, b_f0, Wih_f1, Whh_f1, b_f1,
               Wih_b0, Whh_b0, b_b0, Wih_b1, Whh_b1, b_b1,
               Wlin, blin, futp, outp, h0s, h1s, threadIdx.x, blockIdx.x);
}

extern "C" void kernel_launch(void* const* d_in, const int* in_sizes, int n_in,
                              void* d_out, int out_size, void* d_ws, size_t ws_size,
                              hipStream_t stream) {
  (void)in_sizes; (void)n_in; (void)out_size; (void)d_ws; (void)ws_size;
  lstm_kernel<<<dim3(GRID), dim3(NT), 0, stream>>>(
      d_in[0], d_in[1], d_in[2], d_in[3], d_in[4], d_in[5], d_in[6],
      d_in[7], d_in[8], d_in[9], d_in[10], d_in[11], d_in[12],
      d_in[13], d_in[14], (const int*)d_in[15], d_out);
}